// Round 1
// baseline (285.284 us; speedup 1.0000x reference)
//
#include <hip/hip_runtime.h>
#include <cmath>

#define DEV __device__ __forceinline__

static DEV float rdl(float x, int l) {
  return __int_as_float(__builtin_amdgcn_readlane(__float_as_int(x), l));
}

// broadcast the value held by lane (4j+K) to all lanes of quad j (DPP quad_perm)
template <int K>
static DEV float qb(float x) {
  return __int_as_float(
      __builtin_amdgcn_update_dpp(0, __float_as_int(x), K * 0x55, 0xF, 0xF, true));
}

struct KP {
  const float* tags; const float* lem;
  const float* eWih0; const float* eWhh0; const float* ebih0; const float* ebhh0;
  const float* eWih1; const float* eWhh1; const float* ebih1; const float* ebhh1;
  const float* eWih2; const float* eWhh2; const float* ebih2; const float* ebhh2;
  const float* dWih0; const float* dWhh0; const float* dbih0; const float* dbhh0;
  const float* dWih1; const float* dWhh1; const float* dbih1; const float* dbhh1;
  const float* dWih2; const float* dWhh2; const float* dbih2; const float* dbhh2;
  const float* linW; const float* linb;
  float* outp; float* outt;
  int B;
};

// One wave (64 lanes) per batch chain. 4 chains per 256-thread block.
// lane = 4*j + k : lane owns gate row (k*10 + j); k: 0=i, 1=f, 2=g~, 3=o.
// Lanes 40..63 (j>=10) are clamped to j=9 and compute harmless duplicates.
__global__ __launch_bounds__(256) void seq2seq_kernel(KP P) {
  const int tid = threadIdx.x;
  const int lane = tid & 63;
  const int b = blockIdx.x * 4 + (tid >> 6);

  // --- stage tag-slices of W_ih0 (enc then dec), rows x 63, into LDS ---
  __shared__ float sW[5040];  // [2][40][63]
  for (int i = tid; i < 5040; i += 256) {
    int m = (i >= 2520) ? 1 : 0;
    int r2 = i - m * 2520;
    int rr = r2 / 63;
    int dd = r2 - rr * 63;
    sW[i] = (m ? P.dWih0 : P.eWih0)[rr * 64 + 1 + dd];
  }
  __syncthreads();
  if (b >= P.B) return;

  const int jq = lane >> 2;
  const int kg = lane & 3;
  const int jj = (jq < 10) ? jq : 9;
  const int row = kg * 10 + jj;

  // activation selector: g~ rows use tanh(x) = 2*sigmoid(2x)-1
  const float kneg = (kg == 2) ? -2.0f : -1.0f;
  const float am = (kg == 2) ? 2.0f : 1.0f;
  const float ab = (kg == 2) ? -1.0f : 0.0f;

  auto act = [&](float g) -> float {
    float e = expf(kneg * g);
    float y = 1.0f / (1.0f + e);
    return fmaf(am, y, ab);
  };

  // per-chain uniform data
  float tv = (lane < 63) ? P.tags[(size_t)b * 63 + lane] : 0.0f;
  float lemv = (lane < 32) ? P.lem[(size_t)b * 32 + lane] : 0.0f;

  // --- encoder weights into per-lane registers (lane holds its gate row) ---
  float ew0c = P.eWih0[row * 64];  // column 0 (the char feature)
  float ehh0[10], eih1[10], ehh1[10], eih2[10], ehh2[10];
#pragma unroll
  for (int q = 0; q < 10; q++) {
    ehh0[q] = P.eWhh0[row * 10 + q];
    eih1[q] = P.eWih1[row * 10 + q];
    ehh1[q] = P.eWhh1[row * 10 + q];
    eih2[q] = P.eWih2[row * 10 + q];
    ehh2[q] = P.eWhh2[row * 10 + q];
  }
  float pre0 = P.ebih0[row] + P.ebhh0[row];
  float pre1 = P.ebih1[row] + P.ebhh1[row];
  float pre2 = P.ebih2[row] + P.ebhh2[row];
  float dpre0 = P.dbih0[row] + P.dbhh0[row];

  // fold the (time-constant) tag contribution into the layer-0 biases
  {
    const int ro = row * 63;
    for (int d = 0; d < 63; d++) {
      float ts = rdl(tv, d);
      pre0 = fmaf(sW[ro + d], ts, pre0);
      dpre0 = fmaf(sW[2520 + ro + d], ts, dpre0);
    }
  }

  // state: h replicated via readlane (uniform), c lives per-quad
  float h0[10], h1[10], h2[10];
#pragma unroll
  for (int q = 0; q < 10; q++) { h0[q] = 0.0f; h1[q] = 0.0f; h2[q] = 0.0f; }
  float c0 = 0.0f, c1 = 0.0f, c2 = 0.0f;

  auto update = [&](float a, float& c, float (&h)[10]) {
    float a0 = qb<0>(a);  // sigmoid(i)
    float a1 = qb<1>(a);  // sigmoid(f)
    float a2 = qb<2>(a);  // tanh(g~)
    float a3 = qb<3>(a);  // sigmoid(o)
    c = a1 * c + a0 * a2;
    // stable tanh(c): never overflows
    float e2 = expf(-2.0f * fabsf(c));
    float th = copysignf((1.0f - e2) / (1.0f + e2), c);
    float hv = a3 * th;
#pragma unroll
    for (int q = 0; q < 10; q++) h[q] = rdl(hv, 4 * q);
  };

  // ---------------- encoder: 32 steps ----------------
  for (int t = 0; t < 32; t++) {
    float ch = rdl(lemv, t);
    float g = fmaf(ew0c, ch, pre0);
#pragma unroll
    for (int q = 0; q < 10; q++) g = fmaf(ehh0[q], h0[q], g);
    update(act(g), c0, h0);

    g = pre1;
#pragma unroll
    for (int q = 0; q < 10; q++) g = fmaf(eih1[q], h0[q], g);
#pragma unroll
    for (int q = 0; q < 10; q++) g = fmaf(ehh1[q], h1[q], g);
    update(act(g), c1, h1);

    g = pre2;
#pragma unroll
    for (int q = 0; q < 10; q++) g = fmaf(eih2[q], h1[q], g);
#pragma unroll
    for (int q = 0; q < 10; q++) g = fmaf(ehh2[q], h2[q], g);
    update(act(g), c2, h2);
  }

  // --- decoder weights (loaded after encoder to limit register pressure) ---
  float dw0c = P.dWih0[row * 64];
  float dhh0[10], dih1[10], dhh1[10], dih2[10], dhh2[10];
#pragma unroll
  for (int q = 0; q < 10; q++) {
    dhh0[q] = P.dWhh0[row * 10 + q];
    dih1[q] = P.dWih1[row * 10 + q];
    dhh1[q] = P.dWhh1[row * 10 + q];
    dih2[q] = P.dWih2[row * 10 + q];
    dhh2[q] = P.dWhh2[row * 10 + q];
  }
  float dpre1 = P.dbih1[row] + P.dbhh1[row];
  float dpre2 = P.dbih2[row] + P.dbhh2[row];

  // linear layer: lane holds rows lane and (64+lane if lane<36)
  const int lr1 = lane;
  const int lr2 = (lane < 36) ? (64 + lane) : 99;
  float lw0[10], lw1[10];
#pragma unroll
  for (int q = 0; q < 10; q++) {
    lw0[q] = P.linW[lr1 * 10 + q];
    lw1[q] = P.linW[lr2 * 10 + q];
  }
  float lb0 = P.linb[lr1];
  float lb1 = (lane < 36) ? P.linb[lr2] : -1e30f;

  float* op0 = P.outp + (size_t)b * 3000;
  float tok = 1.0f;   // START
  float tokv = 0.0f;  // lane s accumulates step-s token

  // ---------------- decoder: 30 steps ----------------
  for (int s = 0; s < 30; s++) {
    float g = fmaf(dw0c, tok, dpre0);
#pragma unroll
    for (int q = 0; q < 10; q++) g = fmaf(dhh0[q], h0[q], g);
    update(act(g), c0, h0);

    g = dpre1;
#pragma unroll
    for (int q = 0; q < 10; q++) g = fmaf(dih1[q], h0[q], g);
#pragma unroll
    for (int q = 0; q < 10; q++) g = fmaf(dhh1[q], h1[q], g);
    update(act(g), c1, h1);

    g = dpre2;
#pragma unroll
    for (int q = 0; q < 10; q++) g = fmaf(dih2[q], h1[q], g);
#pragma unroll
    for (int q = 0; q < 10; q++) g = fmaf(dhh2[q], h2[q], g);
    update(act(g), c2, h2);

    // linear + sigmoid
    float z0 = lb0, z1 = lb1;
#pragma unroll
    for (int q = 0; q < 10; q++) {
      z0 = fmaf(lw0[q], h2[q], z0);
      z1 = fmaf(lw1[q], h2[q], z1);
    }
    float p0 = 1.0f / (1.0f + expf(-z0));
    float p1 = 1.0f / (1.0f + expf(-z1));

    float* op = op0 + s * 100;
    op[lane] = p0;
    if (lane < 36) op[64 + lane] = p1;

    // argmax over the 100 probabilities, first-occurrence semantics
    float vm = p0; int im = lane;
    if (p1 > vm) { vm = p1; im = 64 + lane; }
#pragma unroll
    for (int off = 32; off > 0; off >>= 1) {
      float vo = __shfl_xor(vm, off);
      int io = __shfl_xor(im, off);
      if (vo > vm || (vo == vm && io < im)) { vm = vo; im = io; }
    }
    im = __builtin_amdgcn_readfirstlane(im);
    tok = (float)im;
    tokv = (lane == s) ? tok : tokv;
  }

  if (lane < 30) P.outt[(size_t)b * 30 + lane] = tokv;
}

extern "C" void kernel_launch(void* const* d_in, const int* in_sizes, int n_in,
                              void* d_out, int out_size, void* d_ws, size_t ws_size,
                              hipStream_t stream) {
  KP P;
  P.tags = (const float*)d_in[2];
  P.lem = (const float*)d_in[3];
  P.eWih0 = (const float*)d_in[4];  P.eWhh0 = (const float*)d_in[5];
  P.ebih0 = (const float*)d_in[6];  P.ebhh0 = (const float*)d_in[7];
  P.eWih1 = (const float*)d_in[8];  P.eWhh1 = (const float*)d_in[9];
  P.ebih1 = (const float*)d_in[10]; P.ebhh1 = (const float*)d_in[11];
  P.eWih2 = (const float*)d_in[12]; P.eWhh2 = (const float*)d_in[13];
  P.ebih2 = (const float*)d_in[14]; P.ebhh2 = (const float*)d_in[15];
  P.dWih0 = (const float*)d_in[16]; P.dWhh0 = (const float*)d_in[17];
  P.dbih0 = (const float*)d_in[18]; P.dbhh0 = (const float*)d_in[19];
  P.dWih1 = (const float*)d_in[20]; P.dWhh1 = (const float*)d_in[21];
  P.dbih1 = (const float*)d_in[22]; P.dbhh1 = (const float*)d_in[23];
  P.dWih2 = (const float*)d_in[24]; P.dWhh2 = (const float*)d_in[25];
  P.dbih2 = (const float*)d_in[26]; P.dbhh2 = (const float*)d_in[27];
  P.linW = (const float*)d_in[28];
  P.linb = (const float*)d_in[29];

  const int B = in_sizes[3] / 32;  // lemmata is (B, 32)
  P.B = B;
  P.outp = (float*)d_out;
  P.outt = P.outp + (size_t)B * 3000;

  const int blocks = (B + 3) / 4;  // 4 chains (waves) per 256-thread block
  seq2seq_kernel<<<dim3(blocks), dim3(256), 0, stream>>>(P);
}

// Round 2
// 180.902 us; speedup vs baseline: 1.5770x; 1.5770x over previous
//
#include <hip/hip_runtime.h>
#include <cmath>

#define DEV __device__ __forceinline__

static DEV float fast_exp2(float x) {
#if __has_builtin(__builtin_amdgcn_exp2f)
  return __builtin_amdgcn_exp2f(x);
#else
  return exp2f(x);
#endif
}
static DEV float fast_rcp(float x) {
#if __has_builtin(__builtin_amdgcn_rcpf)
  return __builtin_amdgcn_rcpf(x);
#else
  return 1.0f / x;
#endif
}

#define LOG2E 1.4426950408889634f

static DEV float rdl(float x, int l) {
  return __int_as_float(__builtin_amdgcn_readlane(__float_as_int(x), l));
}

// broadcast the value held by lane (4j+K) to all lanes of quad j (DPP quad_perm)
template <int K>
static DEV float qb(float x) {
  return __int_as_float(
      __builtin_amdgcn_update_dpp(0, __float_as_int(x), K * 0x55, 0xF, 0xF, true));
}

struct KP {
  const float* tags; const float* lem;
  const float* eWih0; const float* eWhh0; const float* ebih0; const float* ebhh0;
  const float* eWih1; const float* eWhh1; const float* ebih1; const float* ebhh1;
  const float* eWih2; const float* eWhh2; const float* ebih2; const float* ebhh2;
  const float* dWih0; const float* dWhh0; const float* dbih0; const float* dbhh0;
  const float* dWih1; const float* dWhh1; const float* dbih1; const float* dbhh1;
  const float* dWih2; const float* dWhh2; const float* dbih2; const float* dbhh2;
  const float* linW; const float* linb;
  float* outp; float* outt;
  int B;
};

// One wave (64 lanes) per batch chain. 4 chains per 256-thread block.
// lane = 4*j + k : lane owns gate row (k*10 + j); k: 0=i, 1=f, 2=g~, 3=o.
// Lanes 40..63 (j>=10) are clamped to j=9 and compute harmless duplicates.
__global__ __launch_bounds__(256) void seq2seq_kernel(KP P) {
  const int tid = threadIdx.x;
  const int lane = tid & 63;
  const int b = blockIdx.x * 4 + (tid >> 6);

  // --- stage tag-slices of W_ih0 (enc then dec), rows x 63, into LDS ---
  __shared__ float sW[5040];  // [2][40][63]
  for (int i = tid; i < 5040; i += 256) {
    int m = (i >= 2520) ? 1 : 0;
    int r2 = i - m * 2520;
    int rr = r2 / 63;
    int dd = r2 - rr * 63;
    sW[i] = (m ? P.dWih0 : P.eWih0)[rr * 64 + 1 + dd];
  }
  __syncthreads();
  if (b >= P.B) return;

  const int jq = lane >> 2;
  const int kg = lane & 3;
  const int jj = (jq < 10) ? jq : 9;
  const int row = kg * 10 + jj;

  // unified activation: sigmoid for i,f,o; tanh (=2*sigmoid(2x)-1) for g~
  // act(g) = fma(am, rcp(1 + exp2(kc*g)), ab)
  const float kc = (kg == 2) ? (-2.0f * LOG2E) : (-LOG2E);
  const float am = (kg == 2) ? 2.0f : 1.0f;
  const float ab = (kg == 2) ? -1.0f : 0.0f;

  auto act = [&](float g) -> float {
    float y = fast_rcp(1.0f + fast_exp2(g * kc));
    return fmaf(am, y, ab);
  };

  // per-chain uniform data
  float tv = (lane < 63) ? P.tags[(size_t)b * 63 + lane] : 0.0f;
  float lemv = (lane < 32) ? P.lem[(size_t)b * 32 + lane] : 0.0f;

  // --- encoder weights into per-lane registers (lane holds its gate row) ---
  float ew0c = P.eWih0[row * 64];  // column 0 (the char feature)
  float ehh0[10], eih1[10], ehh1[10], eih2[10], ehh2[10];
#pragma unroll
  for (int q = 0; q < 10; q++) {
    ehh0[q] = P.eWhh0[row * 10 + q];
    eih1[q] = P.eWih1[row * 10 + q];
    ehh1[q] = P.eWhh1[row * 10 + q];
    eih2[q] = P.eWih2[row * 10 + q];
    ehh2[q] = P.eWhh2[row * 10 + q];
  }
  float pre0 = P.ebih0[row] + P.ebhh0[row];
  float pre1 = P.ebih1[row] + P.ebhh1[row];
  float pre2 = P.ebih2[row] + P.ebhh2[row];
  float dpre0 = P.dbih0[row] + P.dbhh0[row];

  // fold the (time-constant) tag contribution into the layer-0 biases
  {
    const int ro = row * 63;
#pragma unroll
    for (int d = 0; d < 63; d++) {
      float ts = rdl(tv, d);
      pre0 = fmaf(sW[ro + d], ts, pre0);
      dpre0 = fmaf(sW[2520 + ro + d], ts, dpre0);
    }
  }

  // state: h replicated via readlane (uniform), c lives per-quad
  float h0[10], h1[10], h2[10];
#pragma unroll
  for (int q = 0; q < 10; q++) { h0[q] = 0.0f; h1[q] = 0.0f; h2[q] = 0.0f; }
  float c0 = 0.0f, c1 = 0.0f, c2 = 0.0f;

  auto update = [&](float a, float& c, float (&h)[10]) {
    float a0 = qb<0>(a);  // sigmoid(i)
    float a1 = qb<1>(a);  // sigmoid(f)
    float a2 = qb<2>(a);  // tanh(g~)
    float a3 = qb<3>(a);  // sigmoid(o)
    c = a1 * c + a0 * a2;
    // tanh(c) = 2*sigmoid(2c)-1; exp2 over/underflow saturates correctly
    float y = fast_rcp(1.0f + fast_exp2(c * (-2.0f * LOG2E)));
    float hv = a3 * fmaf(2.0f, y, -1.0f);
#pragma unroll
    for (int q = 0; q < 10; q++) h[q] = rdl(hv, 4 * q);
  };

  // ---------------- encoder: 32 steps ----------------
  for (int t = 0; t < 32; t++) {
    float ch = rdl(lemv, t);
    float g = fmaf(ew0c, ch, pre0);
#pragma unroll
    for (int q = 0; q < 10; q++) g = fmaf(ehh0[q], h0[q], g);
    update(act(g), c0, h0);

    g = pre1;
#pragma unroll
    for (int q = 0; q < 10; q++) g = fmaf(eih1[q], h0[q], g);
#pragma unroll
    for (int q = 0; q < 10; q++) g = fmaf(ehh1[q], h1[q], g);
    update(act(g), c1, h1);

    g = pre2;
#pragma unroll
    for (int q = 0; q < 10; q++) g = fmaf(eih2[q], h1[q], g);
#pragma unroll
    for (int q = 0; q < 10; q++) g = fmaf(ehh2[q], h2[q], g);
    update(act(g), c2, h2);
  }

  // --- decoder weights (loaded after encoder to limit register pressure) ---
  float dw0c = P.dWih0[row * 64];
  float dhh0[10], dih1[10], dhh1[10], dih2[10], dhh2[10];
#pragma unroll
  for (int q = 0; q < 10; q++) {
    dhh0[q] = P.dWhh0[row * 10 + q];
    dih1[q] = P.dWih1[row * 10 + q];
    dhh1[q] = P.dWhh1[row * 10 + q];
    dih2[q] = P.dWih2[row * 10 + q];
    dhh2[q] = P.dWhh2[row * 10 + q];
  }
  float dpre1 = P.dbih1[row] + P.dbhh1[row];
  float dpre2 = P.dbih2[row] + P.dbhh2[row];

  // linear layer: lane holds rows lane and (64+lane if lane<36)
  const int lr1 = lane;
  const int lr2 = (lane < 36) ? (64 + lane) : 99;
  float lw0[10], lw1[10];
#pragma unroll
  for (int q = 0; q < 10; q++) {
    lw0[q] = P.linW[lr1 * 10 + q];
    lw1[q] = P.linW[lr2 * 10 + q];
  }
  float lb0 = P.linb[lr1];
  float lb1 = (lane < 36) ? P.linb[lr2] : -1e30f;

  float* op0 = P.outp + (size_t)b * 3000;
  float tok = 1.0f;   // START
  float tokv = 0.0f;  // lane s accumulates step-s token

  // ---------------- decoder: 30 steps ----------------
  for (int s = 0; s < 30; s++) {
    float g = fmaf(dw0c, tok, dpre0);
#pragma unroll
    for (int q = 0; q < 10; q++) g = fmaf(dhh0[q], h0[q], g);
    update(act(g), c0, h0);

    g = dpre1;
#pragma unroll
    for (int q = 0; q < 10; q++) g = fmaf(dih1[q], h0[q], g);
#pragma unroll
    for (int q = 0; q < 10; q++) g = fmaf(dhh1[q], h1[q], g);
    update(act(g), c1, h1);

    g = dpre2;
#pragma unroll
    for (int q = 0; q < 10; q++) g = fmaf(dih2[q], h1[q], g);
#pragma unroll
    for (int q = 0; q < 10; q++) g = fmaf(dhh2[q], h2[q], g);
    update(act(g), c2, h2);

    // linear + sigmoid (hardware exp2/rcp)
    float z0 = lb0, z1 = lb1;
#pragma unroll
    for (int q = 0; q < 10; q++) {
      z0 = fmaf(lw0[q], h2[q], z0);
      z1 = fmaf(lw1[q], h2[q], z1);
    }
    float p0 = fast_rcp(1.0f + fast_exp2(z0 * (-LOG2E)));
    float p1 = fast_rcp(1.0f + fast_exp2(z1 * (-LOG2E)));

    float* op = op0 + s * 100;
    op[lane] = p0;
    if (lane < 36) op[64 + lane] = p1;

    // argmax over the 100 probabilities, first-occurrence semantics
    float vm = p0; int im = lane;
    if (p1 > vm) { vm = p1; im = 64 + lane; }
#pragma unroll
    for (int off = 32; off > 0; off >>= 1) {
      float vo = __shfl_xor(vm, off);
      int io = __shfl_xor(im, off);
      if (vo > vm || (vo == vm && io < im)) { vm = vo; im = io; }
    }
    im = __builtin_amdgcn_readfirstlane(im);
    tok = (float)im;
    tokv = (lane == s) ? tok : tokv;
  }

  if (lane < 30) P.outt[(size_t)b * 30 + lane] = tokv;
}

extern "C" void kernel_launch(void* const* d_in, const int* in_sizes, int n_in,
                              void* d_out, int out_size, void* d_ws, size_t ws_size,
                              hipStream_t stream) {
  KP P;
  P.tags = (const float*)d_in[2];
  P.lem = (const float*)d_in[3];
  P.eWih0 = (const float*)d_in[4];  P.eWhh0 = (const float*)d_in[5];
  P.ebih0 = (const float*)d_in[6];  P.ebhh0 = (const float*)d_in[7];
  P.eWih1 = (const float*)d_in[8];  P.eWhh1 = (const float*)d_in[9];
  P.ebih1 = (const float*)d_in[10]; P.ebhh1 = (const float*)d_in[11];
  P.eWih2 = (const float*)d_in[12]; P.eWhh2 = (const float*)d_in[13];
  P.ebih2 = (const float*)d_in[14]; P.ebhh2 = (const float*)d_in[15];
  P.dWih0 = (const float*)d_in[16]; P.dWhh0 = (const float*)d_in[17];
  P.dbih0 = (const float*)d_in[18]; P.dbhh0 = (const float*)d_in[19];
  P.dWih1 = (const float*)d_in[20]; P.dWhh1 = (const float*)d_in[21];
  P.dbih1 = (const float*)d_in[22]; P.dbhh1 = (const float*)d_in[23];
  P.dWih2 = (const float*)d_in[24]; P.dWhh2 = (const float*)d_in[25];
  P.dbih2 = (const float*)d_in[26]; P.dbhh2 = (const float*)d_in[27];
  P.linW = (const float*)d_in[28];
  P.linb = (const float*)d_in[29];

  const int B = in_sizes[3] / 32;  // lemmata is (B, 32)
  P.B = B;
  P.outp = (float*)d_out;
  P.outt = P.outp + (size_t)B * 3000;

  const int blocks = (B + 3) / 4;  // 4 chains (waves) per 256-thread block
  seq2seq_kernel<<<dim3(blocks), dim3(256), 0, stream>>>(P);
}

// Round 3
// 175.031 us; speedup vs baseline: 1.6299x; 1.0335x over previous
//
#include <hip/hip_runtime.h>
#include <cmath>

#define DEV __device__ __forceinline__

static DEV float fast_exp2(float x) {
#if __has_builtin(__builtin_amdgcn_exp2f)
  return __builtin_amdgcn_exp2f(x);
#else
  return exp2f(x);
#endif
}
static DEV float fast_rcp(float x) {
#if __has_builtin(__builtin_amdgcn_rcpf)
  return __builtin_amdgcn_rcpf(x);
#else
  return 1.0f / x;
#endif
}

#define LOG2E 1.4426950408889634f

static DEV float rdl(float x, int l) {
  return __int_as_float(__builtin_amdgcn_readlane(__float_as_int(x), l));
}

// broadcast the value held by lane (4j+K) to all lanes of quad j (DPP quad_perm)
template <int K>
static DEV float qb(float x) {
  return __int_as_float(
      __builtin_amdgcn_update_dpp(0, __float_as_int(x), K * 0x55, 0xF, 0xF, true));
}

// m = max(m, dpp_shift(m)); bound_ctrl=true -> invalid lanes read 0.0f,
// safe as identity since all our probabilities are >= 0.
template <int CTRL>
static DEV float dppmax(float x) {
  float o = __int_as_float(
      __builtin_amdgcn_update_dpp(0, __float_as_int(x), CTRL, 0xF, 0xF, true));
  return fmaxf(x, o);
}

// full wave64 max via DPP (VALU only, no LDS): row_shr 1,2,4,8 then
// row_bcast15, row_bcast31; lane 63 holds the wave max.
static DEV float wavemax_bcast(float m) {
  m = dppmax<0x111>(m);
  m = dppmax<0x112>(m);
  m = dppmax<0x114>(m);
  m = dppmax<0x118>(m);
  m = dppmax<0x142>(m);  // row_bcast:15
  m = dppmax<0x143>(m);  // row_bcast:31
  return rdl(m, 63);
}

struct KP {
  const float* tags; const float* lem;
  const float* eWih0; const float* eWhh0; const float* ebih0; const float* ebhh0;
  const float* eWih1; const float* eWhh1; const float* ebih1; const float* ebhh1;
  const float* eWih2; const float* eWhh2; const float* ebih2; const float* ebhh2;
  const float* dWih0; const float* dWhh0; const float* dbih0; const float* dbhh0;
  const float* dWih1; const float* dWhh1; const float* dbih1; const float* dbhh1;
  const float* dWih2; const float* dWhh2; const float* dbih2; const float* dbhh2;
  const float* linW; const float* linb;
  float* outp; float* outt;
  int B;
};

// One wave (64 lanes) per batch chain. 4 chains per 256-thread block. No LDS.
// lane = 4*j + k : lane owns gate row (k*10 + j); k: 0=i, 1=f, 2=g~, 3=o.
// Lanes 40..63 (j>=10) are clamped to j=9 and compute harmless duplicates.
__global__ __launch_bounds__(256) void seq2seq_kernel(KP P) {
  const int tid = threadIdx.x;
  const int lane = tid & 63;
  const int b = blockIdx.x * 4 + (tid >> 6);
  if (b >= P.B) return;

  const int jq = lane >> 2;
  const int kg = lane & 3;
  const int jj = (jq < 10) ? jq : 9;
  const int row = kg * 10 + jj;

  // unified activation: sigmoid for i,f,o; tanh (=2*sigmoid(2x)-1) for g~
  const float kc = (kg == 2) ? (-2.0f * LOG2E) : (-LOG2E);
  const float am = (kg == 2) ? 2.0f : 1.0f;
  const float ab = (kg == 2) ? -1.0f : 0.0f;

  auto act = [&](float g) -> float {
    float y = fast_rcp(1.0f + fast_exp2(g * kc));
    return fmaf(am, y, ab);
  };

  // per-chain uniform data
  float tv = (lane < 63) ? P.tags[(size_t)b * 63 + lane] : 0.0f;
  float lemv = (lane < 32) ? P.lem[(size_t)b * 32 + lane] : 0.0f;

  // --- fold the (time-constant) tag contribution into the layer-0 biases ---
  // row of W_ih0 = 64 floats = 16 aligned float4s; element 0 is the char col.
  float pre0 = P.ebih0[row] + P.ebhh0[row];
  float dpre0 = P.dbih0[row] + P.dbhh0[row];
  float ew0c, dw0c;
  {
    const float4* e4 = (const float4*)P.eWih0 + row * 16;
    const float4* d4 = (const float4*)P.dWih0 + row * 16;
    float4 we = e4[0], wd = d4[0];
    ew0c = we.x; dw0c = wd.x;
    float t0 = rdl(tv, 0), t1 = rdl(tv, 1), t2 = rdl(tv, 2);
    pre0 = fmaf(we.y, t0, pre0); pre0 = fmaf(we.z, t1, pre0); pre0 = fmaf(we.w, t2, pre0);
    dpre0 = fmaf(wd.y, t0, dpre0); dpre0 = fmaf(wd.z, t1, dpre0); dpre0 = fmaf(wd.w, t2, dpre0);
#pragma unroll
    for (int c = 1; c < 16; c++) {
      float4 e = e4[c], d = d4[c];
      int dd = 4 * c - 1;
      float u0 = rdl(tv, dd), u1 = rdl(tv, dd + 1), u2 = rdl(tv, dd + 2), u3 = rdl(tv, dd + 3);
      pre0 = fmaf(e.x, u0, pre0); pre0 = fmaf(e.y, u1, pre0);
      pre0 = fmaf(e.z, u2, pre0); pre0 = fmaf(e.w, u3, pre0);
      dpre0 = fmaf(d.x, u0, dpre0); dpre0 = fmaf(d.y, u1, dpre0);
      dpre0 = fmaf(d.z, u2, dpre0); dpre0 = fmaf(d.w, u3, dpre0);
    }
  }

  // --- encoder weights into per-lane registers (lane holds its gate row) ---
  float ehh0[10], eih1[10], ehh1[10], eih2[10], ehh2[10];
#pragma unroll
  for (int q = 0; q < 10; q++) {
    ehh0[q] = P.eWhh0[row * 10 + q];
    eih1[q] = P.eWih1[row * 10 + q];
    ehh1[q] = P.eWhh1[row * 10 + q];
    eih2[q] = P.eWih2[row * 10 + q];
    ehh2[q] = P.eWhh2[row * 10 + q];
  }
  float pre1 = P.ebih1[row] + P.ebhh1[row];
  float pre2 = P.ebih2[row] + P.ebhh2[row];

  // state: h replicated via readlane (uniform/SGPR), c lives per-quad
  float h0[10], h1[10], h2[10];
#pragma unroll
  for (int q = 0; q < 10; q++) { h0[q] = 0.0f; h1[q] = 0.0f; h2[q] = 0.0f; }
  float c0 = 0.0f, c1 = 0.0f, c2 = 0.0f;

  auto update = [&](float a, float& c, float (&h)[10]) {
    float a0 = qb<0>(a);  // sigmoid(i)
    float a1 = qb<1>(a);  // sigmoid(f)
    float a2 = qb<2>(a);  // tanh(g~)
    float a3 = qb<3>(a);  // sigmoid(o)
    c = fmaf(a1, c, a0 * a2);
    // tanh(c) = 2*sigmoid(2c)-1; exp2 over/underflow saturates correctly
    float y = fast_rcp(1.0f + fast_exp2(c * (-2.0f * LOG2E)));
    float hv = a3 * fmaf(2.0f, y, -1.0f);
#pragma unroll
    for (int q = 0; q < 10; q++) h[q] = rdl(hv, 4 * q);
  };

  // two-accumulator 10-term dot (halves the dependent-chain latency)
  auto dot2 = [&](const float (&wa)[10], const float (&ha)[10],
                  const float (&wb)[10], const float (&hb)[10], float pre) -> float {
    float ga = pre, gb = 0.0f;
#pragma unroll
    for (int q = 0; q < 10; q += 2) {
      ga = fmaf(wa[q], ha[q], ga);
      gb = fmaf(wa[q + 1], ha[q + 1], gb);
    }
#pragma unroll
    for (int q = 0; q < 10; q += 2) {
      ga = fmaf(wb[q], hb[q], ga);
      gb = fmaf(wb[q + 1], hb[q + 1], gb);
    }
    return ga + gb;
  };
  auto dot1 = [&](const float (&w)[10], const float (&h)[10], float pre) -> float {
    float ga = pre, gb = 0.0f;
#pragma unroll
    for (int q = 0; q < 10; q += 2) {
      ga = fmaf(w[q], h[q], ga);
      gb = fmaf(w[q + 1], h[q + 1], gb);
    }
    return ga + gb;
  };

  // ---------------- encoder: 32 steps ----------------
  for (int t = 0; t < 32; t++) {
    float ch = rdl(lemv, t);
    float g = dot1(ehh0, h0, fmaf(ew0c, ch, pre0));
    update(act(g), c0, h0);
    g = dot2(eih1, h0, ehh1, h1, pre1);
    update(act(g), c1, h1);
    g = dot2(eih2, h1, ehh2, h2, pre2);
    update(act(g), c2, h2);
  }

  // --- decoder weights (loaded after encoder to limit register pressure) ---
  float dhh0[10], dih1[10], dhh1[10], dih2[10], dhh2[10];
#pragma unroll
  for (int q = 0; q < 10; q++) {
    dhh0[q] = P.dWhh0[row * 10 + q];
    dih1[q] = P.dWih1[row * 10 + q];
    dhh1[q] = P.dWhh1[row * 10 + q];
    dih2[q] = P.dWih2[row * 10 + q];
    dhh2[q] = P.dWhh2[row * 10 + q];
  }
  float dpre1 = P.dbih1[row] + P.dbhh1[row];
  float dpre2 = P.dbih2[row] + P.dbhh2[row];

  // linear layer: lane holds rows lane and (64+lane if lane<36)
  const int lr2 = (lane < 36) ? (64 + lane) : 99;
  float lw0[10], lw1[10];
#pragma unroll
  for (int q = 0; q < 10; q++) {
    lw0[q] = P.linW[lane * 10 + q];
    lw1[q] = P.linW[lr2 * 10 + q];
  }
  float lb0 = P.linb[lane];
  float lb1 = (lane < 36) ? P.linb[lr2] : -1e30f;

  float* op0 = P.outp + (size_t)b * 3000;
  float tok = 1.0f;   // START
  float tokv = 0.0f;  // lane s accumulates step-s token

  // ---------------- decoder: 30 steps ----------------
  for (int s = 0; s < 30; s++) {
    float g = dot1(dhh0, h0, fmaf(dw0c, tok, dpre0));
    update(act(g), c0, h0);
    g = dot2(dih1, h0, dhh1, h1, dpre1);
    update(act(g), c1, h1);
    g = dot2(dih2, h1, dhh2, h2, dpre2);
    update(act(g), c2, h2);

    // linear + sigmoid (hardware exp2/rcp)
    float z0 = dot1(lw0, h2, lb0);
    float z1 = dot1(lw1, h2, lb1);
    float p0 = fast_rcp(1.0f + fast_exp2(z0 * (-LOG2E)));
    float p1 = fast_rcp(1.0f + fast_exp2(z1 * (-LOG2E)));  // lanes>=36: exactly 0

    float* op = op0 + s * 100;
    op[lane] = p0;
    if (lane < 36) op[64 + lane] = p1;

    // argmax, first-occurrence: DPP wave-max (VALU) + ballot/ctz (SALU).
    // fmax returns one of its inputs bitwise, so vm matches some p exactly.
    float vm = wavemax_bcast(fmaxf(p0, p1));
    unsigned long long m0 = __ballot(p0 == vm);
    unsigned long long m1 = __ballot(p1 == vm);
    int im = m0 ? (int)__builtin_ctzll(m0) : 64 + (int)__builtin_ctzll(m1);
    tok = (float)im;
    tokv = (lane == s) ? tok : tokv;
  }

  if (lane < 30) P.outt[(size_t)b * 30 + lane] = tokv;
}

extern "C" void kernel_launch(void* const* d_in, const int* in_sizes, int n_in,
                              void* d_out, int out_size, void* d_ws, size_t ws_size,
                              hipStream_t stream) {
  KP P;
  P.tags = (const float*)d_in[2];
  P.lem = (const float*)d_in[3];
  P.eWih0 = (const float*)d_in[4];  P.eWhh0 = (const float*)d_in[5];
  P.ebih0 = (const float*)d_in[6];  P.ebhh0 = (const float*)d_in[7];
  P.eWih1 = (const float*)d_in[8];  P.eWhh1 = (const float*)d_in[9];
  P.ebih1 = (const float*)d_in[10]; P.ebhh1 = (const float*)d_in[11];
  P.eWih2 = (const float*)d_in[12]; P.eWhh2 = (const float*)d_in[13];
  P.ebih2 = (const float*)d_in[14]; P.ebhh2 = (const float*)d_in[15];
  P.dWih0 = (const float*)d_in[16]; P.dWhh0 = (const float*)d_in[17];
  P.dbih0 = (const float*)d_in[18]; P.dbhh0 = (const float*)d_in[19];
  P.dWih1 = (const float*)d_in[20]; P.dWhh1 = (const float*)d_in[21];
  P.dbih1 = (const float*)d_in[22]; P.dbhh1 = (const float*)d_in[23];
  P.dWih2 = (const float*)d_in[24]; P.dWhh2 = (const float*)d_in[25];
  P.dbih2 = (const float*)d_in[26]; P.dbhh2 = (const float*)d_in[27];
  P.linW = (const float*)d_in[28];
  P.linb = (const float*)d_in[29];

  const int B = in_sizes[3] / 32;  // lemmata is (B, 32)
  P.B = B;
  P.outp = (float*)d_out;
  P.outt = P.outp + (size_t)B * 3000;

  const int blocks = (B + 3) / 4;  // 4 chains (waves) per 256-thread block
  seq2seq_kernel<<<dim3(blocks), dim3(256), 0, stream>>>(P);
}